// Round 10
// baseline (3402.329 us; speedup 1.0000x reference)
//
#include <hip/hip_runtime.h>
#include <cstdint>

// Bidirectional masked LSTM encoder, B=64, T=512, E=256, U=512, G=2048.
// R13: DAG skeleton from R9/R10/R12 (proven live 3x; inter-block protocol
// byte-identical here). R12 confirmed the congestion theory (8.65->5.9
// us/level). Residual theory: fan-in jitter -- the consumer starts its
// ~900cy H-load only after the LAST of 32 producer flags, paying
// spread+RT serially. R13 overlaps load ISSUE with straggler detection:
//  - wave0 polls flags continuously (s_sleep removed), publishes a
//    progressive chunk count (0..4) to an LDS word;
//  - all waves gate 4 load-issue chunks (8x dwordx4 each; chunk0 also
//    carries the SC state loads + own-cg gate) on the LDS counter, issuing
//    WITHOUT per-chunk drains;
//  - one s_waitcnt vmcnt(0) + sched_barrier(0) (compiler would hoist
//    register-only MFMAs past a bare asm wait) before all 64 MFMAs.
// Worst case (all producers arrive together) degenerates to R12's single
// batched issue -> strictly no-worse by construction.

#define B_ 64
#define T_ 512
#define E_ 256

typedef __attribute__((ext_vector_type(8))) short bf16x8;
typedef __attribute__((ext_vector_type(4))) float f32x4;
typedef __attribute__((ext_vector_type(2))) float f32x2;
typedef __attribute__((ext_vector_type(2))) unsigned u32x2;

__device__ __forceinline__ unsigned short f2bf(float x) {
  unsigned u = __float_as_uint(x);
  u += 0x7FFFu + ((u >> 16) & 1u);      // round-to-nearest-even
  return (unsigned short)(u >> 16);
}
__device__ __forceinline__ float sigm(float x) { return 1.0f / (1.0f + __expf(-x)); }
__device__ __forceinline__ float tanh_(float x) { return 1.0f - 2.0f / (__expf(2.0f * x) + 1.0f); }

// Gather + f32->bf16 cast of the embedded sequence into [t][b][e] layout.
__global__ void prep_kernel(const int* __restrict__ enc, const float* __restrict__ emb,
                            unsigned short* __restrict__ o) {
  const int bi = blockIdx.x;
  const int t = bi >> 6, b = bi & 63;
  const int tok = enc[b * T_ + t];
  float4 v = ((const float4*)(emb + (size_t)tok * E_))[threadIdx.x];
  ushort4 w;
  w.x = f2bf(v.x); w.y = f2bf(v.y); w.z = f2bf(v.z); w.w = f2bf(v.w);
  ((ushort4*)(o + (size_t)t * (B_ * E_) + b * E_))[threadIdx.x] = w;
}

// One-time weight repack: f32 [K][2048] -> fragment-ordered bf16 (per-thread
// contiguous bf16x8 MFMA B-frags). Layouts as R8..R12 (verified).
__global__ void prep_w(const float* __restrict__ Wf, const float* __restrict__ Uf,
                       const float* __restrict__ Wb, const float* __restrict__ Ub,
                       unsigned short* __restrict__ Uq, unsigned short* __restrict__ Wq) {
  int bi = blockIdx.x;
  const int ns = bi & 1; bi >>= 1;
  const int kk = bi % 24; bi /= 24;
  const int nh = bi & 1; bi >>= 1;
  const int cg = bi & 31; bi >>= 5;
  const int d = bi;
  const int lane = threadIdx.x;
  const int l15 = lane & 15, l4 = lane >> 4;
  const bool isU = (kk < 16);
  const float* src = isU ? (d ? Ub : Uf) : (d ? Wb : Wf);
  const int ks = isU ? kk : (kk - 16);
  const int col = (nh * 2 + ns) * 512 + cg * 16 + l15;
  const int row0 = ks * 32 + l4 * 8;
  bf16x8 f;
#pragma unroll
  for (int i = 0; i < 8; ++i) f[i] = (short)f2bf(src[(size_t)(row0 + i) * 2048 + col]);
  unsigned short* dst = isU
    ? Uq + ((size_t)(((d * 32 + cg) * 2 + nh) * 16 + ks) * 2 + ns) * 512 + lane * 8
    : Wq + ((size_t)(((d * 32 + cg) * 2 + nh) * 8 + ks) * 2 + ns) * 512 + lane * 8;
  *(bf16x8*)dst = f;
}

// ---------------- R13 primary: pipelined step-DAG, one grid ----------------
// grid 32768 = 512 steps x 64 (d,cg). Hst parity [2][2][32cg][64b][16u] bf16;
// SC parity [2][2][32cg][64b][16u] float2 (h,c).
__global__ __launch_bounds__(256, 1)
void lstm_dag(const int* __restrict__ enc, const unsigned short* __restrict__ embq,
              const unsigned short* __restrict__ Uq, const unsigned short* __restrict__ Wq,
              const float* __restrict__ bfv, const float* __restrict__ bbv,
              unsigned short* __restrict__ Hst, f32x2* __restrict__ SC,
              int* __restrict__ flg, float* __restrict__ out) {
  const int s = blockIdx.x >> 6;
  const int inner = blockIdx.x & 63;
  const int d = inner >> 5;
  const int cg = inner & 31;
  const int tid = threadIdx.x;
  const int lane = tid & 63;
  const int wave = tid >> 6;
  const int mh = wave & 1, nh = wave >> 1;
  const int l15 = lane & 15, l4 = lane >> 4;
  const int u0 = cg * 16;
  const int t = d ? (T_ - 1 - s) : s;

  __shared__ float Z[64][68];
  __shared__ int rdy;            // progressive chunk-ready count (0..4)

  // ---- weight frags (coalesced 16B/lane, L2-hot after warmup) ----
  const unsigned short* ub = Uq + ((size_t)((d * 32 + cg) * 2 + nh)) * (16 * 2 * 512);
  const unsigned short* wb = Wq + ((size_t)((d * 32 + cg) * 2 + nh)) * (8 * 2 * 512);
  bf16x8 u_frag[16][2];
#pragma unroll
  for (int ks = 0; ks < 16; ++ks)
#pragma unroll
    for (int ns = 0; ns < 2; ++ns)
      u_frag[ks][ns] = *(const bf16x8*)(ub + (size_t)(ks * 2 + ns) * 512 + lane * 8);
  bf16x8 w_frag[8][2];
#pragma unroll
  for (int ks = 0; ks < 8; ++ks)
#pragma unroll
    for (int ns = 0; ns < 2; ++ns)
      w_frag[ks][ns] = *(const bf16x8*)(wb + (size_t)(ks * 2 + ns) * 512 + lane * 8);

  // ---- emb A-frags + epilogue data ----
  bf16x8 apf[8][2];
  {
    const unsigned short* eT = embq + (size_t)t * (B_ * E_);
#pragma unroll
    for (int ks = 0; ks < 8; ++ks)
#pragma unroll
      for (int ms = 0; ms < 2; ++ms) {
        const int b = mh * 32 + ms * 16 + l15;
        apf[ks][ms] = *(const bf16x8*)(eT + b * E_ + ks * 32 + l4 * 8);
      }
  }
  // epilogue thread map: eb = batch (0..63), uq = unit-quad (0..3)
  const int eb = tid >> 2;
  const int uq = tid & 3;
  const int msk = enc[eb * T_ + t];
  const float* bd = d ? bbv : bfv;
  f32x4 bias[4];
#pragma unroll
  for (int g = 0; g < 4; ++g)
    bias[g] = *(const f32x4*)(bd + g * 512 + u0 + uq * 4);

  f32x4 acc[2][2];
#pragma unroll
  for (int ms = 0; ms < 2; ++ms)
#pragma unroll
    for (int ns = 0; ns < 2; ++ns) acc[ms][ns] = (f32x4)0.0f;

  // ---- x-part: emb @ W (independent of predecessors: before the wait) ----
#pragma unroll
  for (int ks = 0; ks < 8; ++ks)
#pragma unroll
    for (int ms = 0; ms < 2; ++ms)
#pragma unroll
      for (int ns = 0; ns < 2; ++ns)
        acc[ms][ns] = __builtin_amdgcn_mfma_f32_16x16x32_bf16(apf[ks][ms], w_frag[ks][ns],
                                                              acc[ms][ns], 0, 0, 0);

  f32x4 hin0 = (f32x4)0.0f, hin1 = (f32x4)0.0f;  // (h0,c0,h1,c1),(h2,c2,h3,c3)

  if (s > 0) {
    if (tid == 0) *(volatile int*)&rdy = 0;
    __syncthreads();

    // ---- wave0: continuous flag poll (no sleep), publish chunk count to
    //      LDS. Chunk c ready <=> flags of cgs [8c,8c+8) set (chunk 0 also
    //      requires own cg: gates the SC state read). ----
    if (wave == 0) {
      int* fp = flg + ((size_t)s * 2 + d) * 32;
      int got = 0;
      for (;;) {
        int v = __hip_atomic_load(fp + (lane & 31), __ATOMIC_RELAXED, __HIP_MEMORY_SCOPE_AGENT);
        unsigned long long ready = __ballot(v != 0);
        int c = got;
        while (c < 4) {
          unsigned long long m = (0xFFull << (8 * c)) | (0xFFull << (32 + 8 * c));
          if (c == 0) m |= (1ull << cg) | (1ull << (32 + cg));
          if ((ready & m) == m) ++c; else break;
        }
        if (c > got) { got = c; if (lane == 0) *(volatile int*)&rdy = got; }
        if (got == 4) break;
      }
    }

    // ---- all waves: gated load ISSUE (no per-chunk drain). Hst layout
    //      [cg][b][16u]; frag byte off = ks*4096 + ms*512 + (l4>>1)*2048 +
    //      mh*1024 + l15*32 + (l4&1)*16. Chunk c = ks[4c,4c+4) = ptrs 2c,2c+1.
    bf16x8 ha[16][2];
    {
      const char* Hrd = (const char*)(Hst + ((size_t)(s & 1) * 2 + d) * 32768);
      const char* lb = Hrd + (l4 >> 1) * 2048 + mh * 1024 + l15 * 32 + (l4 & 1) * 16;
      const char* sp0 = (const char*)(SC + ((size_t)(s & 1) * 2 + d) * 32768
                                      + (size_t)cg * 1024 + eb * 16 + uq * 4);
      // chunk 0 (+ SC state)
      while (*(volatile int*)&rdy < 1) {}
      __builtin_amdgcn_s_setprio(1);
      {
        const char* pA = lb + 4096;
        const char* pB = lb + 8192 + 4096;
        asm volatile(
          "global_load_dwordx4 %0, %10, off offset:-4096 sc0 sc1\n\t"
          "global_load_dwordx4 %1, %10, off offset:-3584 sc0 sc1\n\t"
          "global_load_dwordx4 %2, %10, off offset:0 sc0 sc1\n\t"
          "global_load_dwordx4 %3, %10, off offset:512 sc0 sc1\n\t"
          "global_load_dwordx4 %4, %11, off offset:-4096 sc0 sc1\n\t"
          "global_load_dwordx4 %5, %11, off offset:-3584 sc0 sc1\n\t"
          "global_load_dwordx4 %6, %11, off offset:0 sc0 sc1\n\t"
          "global_load_dwordx4 %7, %11, off offset:512 sc0 sc1\n\t"
          "global_load_dwordx4 %8, %12, off sc0 sc1\n\t"
          "global_load_dwordx4 %9, %12, off offset:16 sc0 sc1"
          : "=v"(ha[0][0]), "=v"(ha[0][1]), "=v"(ha[1][0]), "=v"(ha[1][1]),
            "=v"(ha[2][0]), "=v"(ha[2][1]), "=v"(ha[3][0]), "=v"(ha[3][1]),
            "=v"(hin0), "=v"(hin1)
          : "v"(pA), "v"(pB), "v"(sp0)
          : "memory");
      }
      // chunks 1..3
#pragma unroll
      for (int c = 1; c < 4; ++c) {
        while (*(volatile int*)&rdy < c + 1) {}
        const char* pA = lb + (size_t)(2 * c) * 8192 + 4096;
        const char* pB = lb + (size_t)(2 * c + 1) * 8192 + 4096;
        asm volatile(
          "global_load_dwordx4 %0, %8, off offset:-4096 sc0 sc1\n\t"
          "global_load_dwordx4 %1, %8, off offset:-3584 sc0 sc1\n\t"
          "global_load_dwordx4 %2, %8, off offset:0 sc0 sc1\n\t"
          "global_load_dwordx4 %3, %8, off offset:512 sc0 sc1\n\t"
          "global_load_dwordx4 %4, %9, off offset:-4096 sc0 sc1\n\t"
          "global_load_dwordx4 %5, %9, off offset:-3584 sc0 sc1\n\t"
          "global_load_dwordx4 %6, %9, off offset:0 sc0 sc1\n\t"
          "global_load_dwordx4 %7, %9, off offset:512 sc0 sc1"
          : "=v"(ha[4 * c][0]), "=v"(ha[4 * c][1]),
            "=v"(ha[4 * c + 1][0]), "=v"(ha[4 * c + 1][1]),
            "=v"(ha[4 * c + 2][0]), "=v"(ha[4 * c + 2][1]),
            "=v"(ha[4 * c + 3][0]), "=v"(ha[4 * c + 3][1])
          : "v"(pA), "v"(pB)
          : "memory");
      }
      // single drain; sched_barrier stops MFMAs being hoisted above it
      asm volatile("s_waitcnt vmcnt(0)" ::: "memory");
      __builtin_amdgcn_sched_barrier(0);
    }
#pragma unroll
    for (int ks = 0; ks < 16; ++ks) {
      acc[0][0] = __builtin_amdgcn_mfma_f32_16x16x32_bf16(ha[ks][0], u_frag[ks][0], acc[0][0], 0, 0, 0);
      acc[0][1] = __builtin_amdgcn_mfma_f32_16x16x32_bf16(ha[ks][0], u_frag[ks][1], acc[0][1], 0, 0, 0);
      acc[1][0] = __builtin_amdgcn_mfma_f32_16x16x32_bf16(ha[ks][1], u_frag[ks][0], acc[1][0], 0, 0, 0);
      acc[1][1] = __builtin_amdgcn_mfma_f32_16x16x32_bf16(ha[ks][1], u_frag[ks][1], acc[1][1], 0, 0, 0);
    }
  }

  // ---- regroup gates per (b,u) via LDS ----
#pragma unroll
  for (int ms = 0; ms < 2; ++ms)
#pragma unroll
    for (int ns = 0; ns < 2; ++ns)
#pragma unroll
      for (int r = 0; r < 4; ++r)
        Z[mh * 32 + ms * 16 + l4 * 4 + r][nh * 32 + ns * 16 + l15] = acc[ms][ns][r];
  __syncthreads();

  // ---- cell + masked carry: thread = (batch eb, 4 units uq*4..+3) ----
  f32x4 vi = *(const f32x4*)&Z[eb][uq * 4];
  f32x4 vf = *(const f32x4*)&Z[eb][16 + uq * 4];
  f32x4 vg = *(const f32x4*)&Z[eb][32 + uq * 4];
  f32x4 vo = *(const f32x4*)&Z[eb][48 + uq * 4];
  float hv[4], cv[4];
  {
    const bool m = (msk != 0);
    float hi_[4] = {hin0[0], hin0[2], hin1[0], hin1[2]};
    float ci_[4] = {hin0[1], hin0[3], hin1[1], hin1[3]};
#pragma unroll
    for (int i = 0; i < 4; ++i) {
      float ig = sigm(vi[i] + bias[0][i]);
      float fg = sigm(vf[i] + bias[1][i]);
      float gg = tanh_(vg[i] + bias[2][i]);
      float og = sigm(vo[i] + bias[3][i]);
      float cn = fg * ci_[i] + ig * gg;
      float hn = og * tanh_(cn);
      hv[i] = m ? hn : hi_[i];
      cv[i] = m ? cn : ci_[i];
    }
  }

  // ---- publish H(s+1) bf16 (1x dwordx2) + (h,c) state (2x dwordx4):
  //      coalesced block-owned lines, ONE drain ----
  {
    u32x2 hu;
    hu[0] = (unsigned)f2bf(hv[0]) | ((unsigned)f2bf(hv[1]) << 16);
    hu[1] = (unsigned)f2bf(hv[2]) | ((unsigned)f2bf(hv[3]) << 16);
    f32x4 sc0v, sc1v;
    sc0v[0] = hv[0]; sc0v[1] = cv[0]; sc0v[2] = hv[1]; sc0v[3] = cv[1];
    sc1v[0] = hv[2]; sc1v[1] = cv[2]; sc1v[2] = hv[3]; sc1v[3] = cv[3];
    char* hp = (char*)(Hst + ((size_t)((s + 1) & 1) * 2 + d) * 32768
                       + (size_t)cg * 1024 + eb * 16 + uq * 4);
    char* scp = (char*)(SC + ((size_t)((s + 1) & 1) * 2 + d) * 32768
                        + (size_t)cg * 1024 + eb * 16 + uq * 4);
    asm volatile(
      "global_store_dwordx2 %0, %2, off sc0 sc1\n\t"
      "global_store_dwordx4 %1, %3, off sc0 sc1\n\t"
      "global_store_dwordx4 %1, %4, off offset:16 sc0 sc1\n\t"
      "s_waitcnt vmcnt(0)"
      :: "v"(hp), "v"(scp), "v"(hu), "v"(sc0v), "v"(sc1v)
      : "memory");
  }
  __syncthreads();   // all waves' publishes drained before the flag
  if (tid == 0)
    __hip_atomic_store(flg + ((size_t)(s + 1) * 2 + d) * 32 + cg, 1,
                       __ATOMIC_RELAXED, __HIP_MEMORY_SCOPE_AGENT);
  __builtin_amdgcn_s_setprio(0);

  // ---- out stores (HBM, off the dependency chain, dwordx4) ----
  {
    f32x4 ov, cvv;
#pragma unroll
    for (int i = 0; i < 4; ++i) { ov[i] = hv[i]; cvv[i] = cv[i]; }
    *(f32x4*)&out[((size_t)eb * T_ + t) * 1024 + d * 512 + u0 + uq * 4] = ov;
    if (s == T_ - 1) {
      *(f32x4*)&out[33554432u + (size_t)eb * 1024 + d * 512 + u0 + uq * 4] = ov;
      *(f32x4*)&out[33619968u + (size_t)eb * 1024 + d * 512 + u0 + uq * 4] = cvv;
    }
  }
}

// ---------------- R8 fallback: step-per-launch (verbatim, proven) ----------
__global__ __launch_bounds__(256, 1)
void lstm_step(const int s, const int* __restrict__ enc, const unsigned short* __restrict__ embq,
               const unsigned short* __restrict__ Uq, const unsigned short* __restrict__ Wq,
               const float* __restrict__ bfv, const float* __restrict__ bbv,
               unsigned short* __restrict__ Hbf, float* __restrict__ Hf32,
               float* __restrict__ Cst, float* __restrict__ out) {
  const int tid = threadIdx.x;
  const int lane = tid & 63;
  const int wave = tid >> 6;
  const int mh = wave & 1, nh = wave >> 1;
  const int l15 = lane & 15, l4 = lane >> 4;
  const int d = blockIdx.x >> 5;
  const int cg = blockIdx.x & 31;
  const int u0 = cg * 16;
  const int t = d ? (T_ - 1 - s) : s;

  __shared__ float Z[64][68];

  const unsigned short* ub = Uq + ((size_t)((d * 32 + cg) * 2 + nh)) * (16 * 2 * 512);
  const unsigned short* wb = Wq + ((size_t)((d * 32 + cg) * 2 + nh)) * (8 * 2 * 512);
  bf16x8 u_frag[16][2];
#pragma unroll
  for (int ks = 0; ks < 16; ++ks)
#pragma unroll
    for (int ns = 0; ns < 2; ++ns)
      u_frag[ks][ns] = *(const bf16x8*)(ub + (size_t)(ks * 2 + ns) * 512 + lane * 8);
  bf16x8 w_frag[8][2];
#pragma unroll
  for (int ks = 0; ks < 8; ++ks)
#pragma unroll
    for (int ns = 0; ns < 2; ++ns)
      w_frag[ks][ns] = *(const bf16x8*)(wb + (size_t)(ks * 2 + ns) * 512 + lane * 8);

  bf16x8 apf[8][2];
  {
    const unsigned short* eT = embq + (size_t)t * (B_ * E_);
#pragma unroll
    for (int ks = 0; ks < 8; ++ks)
#pragma unroll
      for (int ms = 0; ms < 2; ++ms) {
        const int b = mh * 32 + ms * 16 + l15;
        apf[ks][ms] = *(const bf16x8*)(eT + b * E_ + ks * 32 + l4 * 8);
      }
  }
  const int ej = tid & 15;
  const int ebg = tid >> 4;
  int mpf[4];
#pragma unroll
  for (int r = 0; r < 4; ++r) mpf[r] = enc[(ebg * 4 + r) * T_ + t];

  f32x4 acc[2][2];
#pragma unroll
  for (int ms = 0; ms < 2; ++ms)
#pragma unroll
    for (int ns = 0; ns < 2; ++ns) acc[ms][ns] = (f32x4)0.0f;

#pragma unroll
  for (int ks = 0; ks < 8; ++ks)
#pragma unroll
    for (int ms = 0; ms < 2; ++ms)
#pragma unroll
      for (int ns = 0; ns < 2; ++ns)
        acc[ms][ns] = __builtin_amdgcn_mfma_f32_16x16x32_bf16(apf[ks][ms], w_frag[ks][ns],
                                                              acc[ms][ns], 0, 0, 0);

  if (s > 0) {
    const unsigned short* Hrd = Hbf + ((size_t)((s & 1) * 2 + d)) * (B_ * 512);
    bf16x8 ha[16][2];
#pragma unroll
    for (int ks = 0; ks < 16; ++ks)
#pragma unroll
      for (int ms = 0; ms < 2; ++ms) {
        const int b = mh * 32 + ms * 16 + l15;
        ha[ks][ms] = *(const bf16x8*)(Hrd + (size_t)b * 512 + ks * 32 + l4 * 8);
      }
#pragma unroll
    for (int ks = 0; ks < 16; ++ks) {
      acc[0][0] = __builtin_amdgcn_mfma_f32_16x16x32_bf16(ha[ks][0], u_frag[ks][0], acc[0][0], 0, 0, 0);
      acc[0][1] = __builtin_amdgcn_mfma_f32_16x16x32_bf16(ha[ks][0], u_frag[ks][1], acc[0][1], 0, 0, 0);
      acc[1][0] = __builtin_amdgcn_mfma_f32_16x16x32_bf16(ha[ks][1], u_frag[ks][0], acc[1][0], 0, 0, 0);
      acc[1][1] = __builtin_amdgcn_mfma_f32_16x16x32_bf16(ha[ks][1], u_frag[ks][1], acc[1][1], 0, 0, 0);
    }
  }

#pragma unroll
  for (int ms = 0; ms < 2; ++ms)
#pragma unroll
    for (int ns = 0; ns < 2; ++ns)
#pragma unroll
      for (int r = 0; r < 4; ++r)
        Z[mh * 32 + ms * 16 + l4 * 4 + r][nh * 32 + ns * 16 + l15] = acc[ms][ns][r];
  __syncthreads();

  const float* bd = d ? bbv : bfv;
  float bias[4];
#pragma unroll
  for (int g = 0; g < 4; ++g) bias[g] = bd[g * 512 + u0 + ej];

  float* Hf = Hf32 + (size_t)d * (B_ * 512);
  float* Cf = Cst + (size_t)d * (B_ * 512);
  unsigned short* Hwr = Hbf + ((size_t)(((s + 1) & 1) * 2 + d)) * (B_ * 512);
  const bool last = (s == T_ - 1);
#pragma unroll
  for (int r = 0; r < 4; ++r) {
    const int b = ebg * 4 + r;
    const size_t si = (size_t)b * 512 + u0 + ej;
    float zi = Z[b][ej] + bias[0];
    float zf = Z[b][16 + ej] + bias[1];
    float zg = Z[b][32 + ej] + bias[2];
    float zo = Z[b][48 + ej] + bias[3];
    float ig = sigm(zi), fg = sigm(zf), gg = tanh_(zg), og = sigm(zo);
    float hp = Hf[si], cp = Cf[si];
    float cn = fg * cp + ig * gg;
    float hn = og * tanh_(cn);
    const bool m = (mpf[r] != 0);
    float hv = m ? hn : hp;
    float cv = m ? cn : cp;
    Hf[si] = hv;
    Cf[si] = cv;
    Hwr[si] = f2bf(hv);
    out[((size_t)b * T_ + t) * 1024 + d * 512 + u0 + ej] = hv;
    if (last) {
      out[33554432u + (size_t)b * 1024 + d * 512 + u0 + ej] = hv;
      out[33619968u + (size_t)b * 1024 + d * 512 + u0 + ej] = cv;
    }
  }
}

extern "C" void kernel_launch(void* const* d_in, const int* in_sizes, int n_in,
                              void* d_out, int out_size, void* d_ws, size_t ws_size,
                              hipStream_t stream) {
  const int* enc = (const int*)d_in[0];
  const float* emb = (const float*)d_in[1];
  const float* Wf = (const float*)d_in[2];
  const float* Uf = (const float*)d_in[3];
  const float* bf = (const float*)d_in[4];
  const float* Wb = (const float*)d_in[5];
  const float* Ub = (const float*)d_in[6];
  const float* bb = (const float*)d_in[7];
  float* out = (float*)d_out;
  char* ws = (char*)d_ws;

  // shared prep regions
  unsigned short* embq = (unsigned short*)ws;                  // 16 MiB
  unsigned short* Uq  = (unsigned short*)(ws + 16777216u);     // 4 MiB
  unsigned short* Wq  = (unsigned short*)(ws + 20971520u);     // 2 MiB

  // primary (DAG) layout: 25.6 MB total
  const size_t OFF_HST = 23068672u;                            // [2][2][32][64][16] bf16, 256 KiB
  const size_t OFF_SC  = 23330816u;                            // [2][2][32][64][16] float2, 2 MiB
  const size_t OFF_FLG = 25427968u;                            // [513][2][32] int
  const size_t NEED    = 25559296u;

  prep_kernel<<<32768, 64, 0, stream>>>(enc, emb, embq);
  prep_w<<<6144, 64, 0, stream>>>(Wf, Uf, Wb, Ub, Uq, Wq);

  if (ws_size >= NEED) {
    unsigned short* Hst = (unsigned short*)(ws + OFF_HST);
    f32x2* SC = (f32x2*)(ws + OFF_SC);
    int*   flg = (int*)(ws + OFF_FLG);
    hipMemsetAsync(ws + OFF_SC, 0, NEED - OFF_SC, stream);
    lstm_dag<<<32768, 256, 0, stream>>>(enc, embq, Uq, Wq, bf, bb,
                                        Hst, SC, flg, out);
  } else {
    // fallback: verbatim R8 step-per-launch (proven pass at 7037 us)
    unsigned short* Hbf = (unsigned short*)(ws + 23068672u);
    float* Hf32 = (float*)(ws + 23330816u);
    float* Cst  = (float*)(ws + 23592960u);
    hipMemsetAsync(ws + 23068672u, 0, 786432u, stream);
    for (int s = 0; s < 512; ++s)
      lstm_step<<<64, 256, 0, stream>>>(s, enc, embq, Uq, Wq, bf, bb, Hbf, Hf32, Cst, out);
  }
}